// Round 17
// baseline (537.295 us; speedup 1.0000x reference)
//
#include <hip/hip_runtime.h>
#include <math.h>

namespace {

typedef __attribute__((ext_vector_type(8))) short short8;
typedef __attribute__((ext_vector_type(4))) float f32x4;

constexpr float kPI = 3.14159265358979323846f;

__device__ __forceinline__ unsigned short f2bf(float f) {
    unsigned int u = __float_as_uint(f);
    u += 0x7fffu + ((u >> 16) & 1u);
    return (unsigned short)(u >> 16);
}

__device__ __forceinline__ short8 pack8(const float* f) {
    short8 r;
    #pragma unroll
    for (int i = 0; i < 8; ++i) r[i] = (short)f2bf(f[i]);
    return r;
}

__device__ __forceinline__ f32x4 MFMA(short8 a, short8 b, f32x4 c) {
    return __builtin_amdgcn_mfma_f32_16x16x32_bf16(a, b, c, 0, 0, 0);
}

// ---- weight pre-arrangement into B-fragment order (bf16) + cos/sin table ----
// chunk = (adv, kstep, ntile): 64 lanes x 8 bf16; lane l holds
// B[k = kstep*32 + (l>>4)*8 + i][col = ntile*16 + (l&15)].
// arr==3 (c2<128): csTab[axis][pos][r] = (cos,sin) of the RoPE phase --
// line/batch-independent, so it is computed ONCE here instead of per-block
// (round-10's in-loop sincos was the register-pressure source of its 110 MB
// spill traffic; round-12's LDS table cost 16 KB LDS + a 3rd barrier).
__global__ __launch_bounds__(256)
void prep_weights(const float* __restrict__ Wq, const float* __restrict__ Wk,
                  const float* __restrict__ Wv, const float* __restrict__ Wo,
                  const float* __restrict__ xpos, const float* __restrict__ ypos,
                  const float* __restrict__ rfreq,
                  short* __restrict__ wsQ, short* __restrict__ wsKV,
                  short* __restrict__ wsO, float2* __restrict__ csTab)
{
    const int cid = blockIdx.x * 4 + (threadIdx.x >> 6);
    const int l = threadIdx.x & 63;
    const int lr = l & 15, lk = l >> 4;
    const int arr = cid >> 10, c2 = cid & 1023;
    if (arr == 3) {
        if (c2 < 128) {
            const int idx = c2 * 64 + l;            // 0..8191
            const int axis = idx >> 12;
            const int pos = (idx >> 7) & 31;
            const int r = idx & 127;
            const int h = r & 15;
            const float s0 = kPI / (1.0f + (29.0f / 15.0f) * (float)h);
            const float s1 = kPI / (0.1f + 0.06f * (float)h);
            const float* posv = (axis == 0) ? ypos : xpos;
            const float phi = rfreq[r * 2 + 0] * s0 * posv[pos * 2 + 0] +
                              rfreq[r * 2 + 1] * s1 * posv[pos * 2 + 1];
            float sv, cv;
            __sincosf(phi, &sv, &cv);
            csTab[idx] = make_float2(cv, sv);
        }
        return;
    }
    const int adv = c2 >> 7, ks = (c2 >> 4) & 7, nt = c2 & 15;
    const int c0 = ks * 32 + lk * 8;
    float v[8];
    if (arr == 0) {                       // Wq[c][adv][j], j in [0,256)
        const int j = nt * 16 + lr;
        #pragma unroll
        for (int i = 0; i < 8; ++i)
            v[i] = Wq[((size_t)(c0 + i) * 8 + adv) * 256 + j];
    } else if (arr == 1) {                // K (nt<8) then V (nt>=8), j in [0,128)
        if (nt < 8) {
            const int j = nt * 16 + lr;
            #pragma unroll
            for (int i = 0; i < 8; ++i)
                v[i] = Wk[((size_t)(c0 + i) * 8 + adv) * 128 + j];
        } else {
            const int j = (nt - 8) * 16 + lr;
            #pragma unroll
            for (int i = 0; i < 8; ++i)
                v[i] = Wv[((size_t)(c0 + i) * 8 + adv) * 128 + j];
        }
    } else {                              // Wo[adv][j][c]: k=j, col=c
        const int cc = nt * 16 + lr;
        #pragma unroll
        for (int i = 0; i < 8; ++i)
            v[i] = Wo[((size_t)adv * 256 + (c0 + i)) * 256 + cc];
    }
    short* dst = (arr == 0 ? wsQ : arr == 1 ? wsKV : wsO) + (size_t)c2 * 512 + l * 8;
    *(short8*)dst = pack8(v);
}

// ---- fused per-line axial attention; all four GEMMs + attention on MFMA ----
// Round-10 structure (best measured) with the RoPE cos/sin read from a global
// table (csv, L1/L2-resident, loads depend only on indices -> hoisted into the
// MFMA k-loop shadow). Epilogues fully unrolled (compile-time acc indices).
// LDS = 72 KB -> 2 blocks/CU under __launch_bounds__(512,4).
template <int AXIS, bool ACCUM>
__global__ __launch_bounds__(512, 4)
void axial_attn_mfma(const float* __restrict__ x,
                     const float* __restrict__ bvp,
                     const float2* __restrict__ csv,
                     const short* __restrict__ wsQ,
                     const short* __restrict__ wsKV,
                     const short* __restrict__ wsO,
                     float* __restrict__ out)
{
    __shared__ __align__(16) short xs[32 * 256];    // x line bf16, elem ^ ((row&7)<<3)
    __shared__ __align__(16) short qbuf[32 * 256];  // Qr bf16, same swizzle
    __shared__ __align__(16) short kbuf[32 * 256];  // Kr bf16 (with m), same swizzle
    __shared__ __align__(16) short vbuf[4 * 32 * 32]; // V^T bf16 [kk][dv][s ^ ((dv&3)<<3)]
    __shared__ __align__(16) short obuf[32 * 256];  // attn out bf16, same swizzle

    const int t = threadIdx.x;
    const int b = blockIdx.x >> 5;
    const int line = blockIdx.x & 31;
    const int w = t >> 6, l = t & 63;
    const int lr = l & 15, lk = l >> 4;
    const int p01 = l & 1;

    // ---- stage x line into xs (bf16, swizzled): 16 elems/thread ----
    {
        const int row = t >> 4;
        const int c0 = (t & 15) * 16;
        const int gy = (AXIS == 0) ? row : line;
        const int gx = (AXIS == 0) ? line : row;
        const float* px = x + ((size_t)((b * 32 + gy) * 32 + gx)) * 256 + c0;
        float tmp[16];
        #pragma unroll
        for (int i = 0; i < 16; i += 4) {
            const float4 a = *(const float4*)(px + i);
            tmp[i] = a.x; tmp[i + 1] = a.y; tmp[i + 2] = a.z; tmp[i + 3] = a.w;
        }
        const int swz = (row & 7) << 3;
        *(short8*)&xs[row * 256 + (c0 ^ swz)] = pack8(tmp);
        *(short8*)&xs[row * 256 + ((c0 + 8) ^ swz)] = pack8(tmp + 8);
    }
    __syncthreads();

    f32x4 oacc[2][2] = {};
    const short8* wsQv  = (const short8*)wsQ;
    const short8* wsKVv = (const short8*)wsKV;
    const short8* wsOv  = (const short8*)wsO;
    const int m_w = w >> 2, kk_w = w & 3;
    const int aswz = (lr & 7) << 3;   // row&7 == lr&7 for rows lr and 16+lr

    for (int dvi = 0; dvi < 4; ++dvi) {
        const int adv = AXIS * 4 + dvi;
        const float sgn = (dvi < 2) ? 1.0f : -1.0f;   // d = dvi>>1

        // ---------- Q projection + RoPE (global table) -> qbuf bf16 ----------
        {
            f32x4 acc[2][2] = {};
            #pragma unroll 2
            for (int ks = 0; ks < 8; ++ks) {
                const int e = (ks * 32 + lk * 8) ^ aswz;
                const short8 a0 = *(const short8*)&xs[lr * 256 + e];
                const short8 a1 = *(const short8*)&xs[(16 + lr) * 256 + e];
                const short8 b0 = wsQv[(size_t)((adv * 8 + ks) * 16 + w * 2 + 0) * 64 + l];
                const short8 b1 = wsQv[(size_t)((adv * 8 + ks) * 16 + w * 2 + 1) * 64 + l];
                acc[0][0] = MFMA(a0, b0, acc[0][0]);
                acc[1][0] = MFMA(a1, b0, acc[1][0]);
                acc[0][1] = MFMA(a0, b1, acc[0][1]);
                acc[1][1] = MFMA(a1, b1, acc[1][1]);
            }
            #pragma unroll
            for (int mt = 0; mt < 2; ++mt)
                #pragma unroll
                for (int nt = 0; nt < 2; ++nt) {
                    const int h = (nt * 16 + lr) >> 1;
                    const int base = m_w * 64 + kk_w * 16 + h;
                    const int col = w * 32 + nt * 16 + lr;
                    #pragma unroll
                    for (int r = 0; r < 4; ++r) {
                        const float own = acc[mt][nt][r];
                        const float oth = __shfl_xor(own, 1);
                        const int pos = mt * 16 + lk * 4 + r;
                        const float2 cs = csv[pos * 128 + base];
                        const float rv = (p01 == 0) ? cs.x * own + sgn * cs.y * oth
                                                    : cs.x * own - sgn * cs.y * oth;
                        qbuf[pos * 256 + (col ^ ((pos & 7) << 3))] = (short)f2bf(rv);
                    }
                }
        }

        // ---------- K/V projection (waves 0-3: K both m; waves 4-7: V^T) ----------
        {
            f32x4 acc[2][2] = {};
            #pragma unroll 2
            for (int ks = 0; ks < 8; ++ks) {
                const int e = (ks * 32 + lk * 8) ^ aswz;
                const short8 a0 = *(const short8*)&xs[lr * 256 + e];
                const short8 a1 = *(const short8*)&xs[(16 + lr) * 256 + e];
                const short8 b0 = wsKVv[(size_t)((adv * 8 + ks) * 16 + w * 2 + 0) * 64 + l];
                const short8 b1 = wsKVv[(size_t)((adv * 8 + ks) * 16 + w * 2 + 1) * 64 + l];
                acc[0][0] = MFMA(a0, b0, acc[0][0]);
                acc[1][0] = MFMA(a1, b0, acc[1][0]);
                acc[0][1] = MFMA(a0, b1, acc[0][1]);
                acc[1][1] = MFMA(a1, b1, acc[1][1]);
            }
            if (w < 4) {
                #pragma unroll
                for (int mt = 0; mt < 2; ++mt)
                    #pragma unroll
                    for (int nt = 0; nt < 2; ++nt) {
                        const int h = (nt * 16 + lr) >> 1;
                        const int jl = nt * 16 + lr;
                        #pragma unroll
                        for (int r = 0; r < 4; ++r) {
                            const float own = acc[mt][nt][r];
                            const float oth = __shfl_xor(own, 1);
                            const int pos = mt * 16 + lk * 4 + r;
                            #pragma unroll
                            for (int m2 = 0; m2 < 2; ++m2) {
                                const float2 cs = csv[pos * 128 + m2 * 64 + w * 16 + h];
                                const float rv = (p01 == 0) ? cs.x * own + sgn * cs.y * oth
                                                            : cs.x * own - sgn * cs.y * oth;
                                const int col = (m2 * 4 + w) * 32 + jl;
                                kbuf[pos * 256 + (col ^ ((pos & 7) << 3))] = (short)f2bf(rv);
                            }
                        }
                    }
            } else {
                const int kk = w - 4;
                #pragma unroll
                for (int nt = 0; nt < 2; ++nt) {
                    const int dv = nt * 16 + lr;
                    const float bvv = bvp[adv * 128 + kk * 32 + dv];
                    #pragma unroll
                    for (int mt = 0; mt < 2; ++mt)
                        #pragma unroll
                        for (int r = 0; r < 4; ++r) {
                            const int s = mt * 16 + lk * 4 + r;
                            // swizzle restricted to bits 3-4: s has only 5 bits.
                            vbuf[kk * 1024 + dv * 32 + (s ^ ((dv & 3) << 3))] =
                                (short)f2bf(acc[mt][nt][r] + bvv);
                        }
                }
            }
        }
        __syncthreads();

        // ---------- attention (MFMA): wave g; scores^T = mfma(Kr, Qr) ----------
        {
            const int g = w;
            short8 ka[2], qa[2];
            #pragma unroll
            for (int st = 0; st < 2; ++st) {
                const int row = st * 16 + lr;
                ka[st] = *(const short8*)&kbuf[row * 256 + ((g * 32 + lk * 8) ^ ((row & 7) << 3))];
            }
            #pragma unroll
            for (int qt = 0; qt < 2; ++qt) {
                const int row = qt * 16 + lr;
                qa[qt] = *(const short8*)&qbuf[row * 256 + ((g * 32 + lk * 8) ^ ((row & 7) << 3))];
            }
            f32x4 d[2][2] = {};
            #pragma unroll
            for (int st = 0; st < 2; ++st)
                #pragma unroll
                for (int qt = 0; qt < 2; ++qt)
                    d[st][qt] = MFMA(ka[st], qa[qt], d[st][qt]);

            // sigmoid + pack pairs (consecutive s) to bf16 — plain bit ops
            unsigned int pk[2][2][2];
            #pragma unroll
            for (int st = 0; st < 2; ++st)
                #pragma unroll
                for (int qt = 0; qt < 2; ++qt)
                    #pragma unroll
                    for (int h2 = 0; h2 < 2; ++h2) {
                        const float za = __builtin_amdgcn_rcpf(1.0f + __expf(-d[st][qt][2 * h2]));
                        const float zb = __builtin_amdgcn_rcpf(1.0f + __expf(-d[st][qt][2 * h2 + 1]));
                        pk[st][qt][h2] = (unsigned int)f2bf(za) |
                                         ((unsigned int)f2bf(zb) << 16);
                    }

            // redistribute D^T -> P A-frag: lane (lk,lr) needs P[s=lk*8+i][q=qt*16+lr]
            const int srcA = ((lk & 1) * 2) * 16 + lr;
            short8 pa[2];
            #pragma unroll
            for (int qt = 0; qt < 2; ++qt) {
                union { unsigned int u[4]; short8 s; } uu;
                #pragma unroll
                for (int jp = 0; jp < 4; ++jp) {
                    const int src = srcA + (jp >> 1) * 16;
                    const int v0 = __shfl((int)pk[0][qt][jp & 1], src, 64);
                    const int v1 = __shfl((int)pk[1][qt][jp & 1], src, 64);
                    uu.u[jp] = (lk < 2) ? (unsigned int)v0 : (unsigned int)v1;
                }
                pa[qt] = uu.s;
            }

            // PV: B-frag from V^T; o[q][dv]
            const int kkg = g & 3;
            short8 vb2[2];
            #pragma unroll
            for (int dvt = 0; dvt < 2; ++dvt) {
                const int dv = dvt * 16 + lr;
                vb2[dvt] = *(const short8*)&vbuf[kkg * 1024 + dv * 32 + ((lk * 8) ^ ((dv & 3) << 3))];
            }
            f32x4 o2[2][2] = {};
            #pragma unroll
            for (int qt = 0; qt < 2; ++qt)
                #pragma unroll
                for (int dvt = 0; dvt < 2; ++dvt)
                    o2[qt][dvt] = MFMA(pa[qt], vb2[dvt], o2[qt][dvt]);

            // write o -> obuf bf16 (swizzled like qbuf)
            #pragma unroll
            for (int qt = 0; qt < 2; ++qt)
                #pragma unroll
                for (int dvt = 0; dvt < 2; ++dvt)
                    #pragma unroll
                    for (int r = 0; r < 4; ++r) {
                        const int q = qt * 16 + lk * 4 + r;
                        const int col = g * 32 + dvt * 16 + lr;
                        obuf[q * 256 + (col ^ ((q & 7) << 3))] = (short)f2bf(o2[qt][dvt][r]);
                    }
        }
        __syncthreads();

        // ---------- out projection: oacc += o(bf16) x Wo_frag ----------
        {
            #pragma unroll 2
            for (int ks = 0; ks < 8; ++ks) {
                const int e = (ks * 32 + lk * 8) ^ aswz;
                const short8 a0 = *(const short8*)&obuf[lr * 256 + e];
                const short8 a1 = *(const short8*)&obuf[(16 + lr) * 256 + e];
                const short8 b0 = wsOv[(size_t)((adv * 8 + ks) * 16 + w * 2 + 0) * 64 + l];
                const short8 b1 = wsOv[(size_t)((adv * 8 + ks) * 16 + w * 2 + 1) * 64 + l];
                oacc[0][0] = MFMA(a0, b0, oacc[0][0]);
                oacc[1][0] = MFMA(a1, b0, oacc[1][0]);
                oacc[0][1] = MFMA(a0, b1, oacc[0][1]);
                oacc[1][1] = MFMA(a1, b1, oacc[1][1]);
            }
        }
        // next-slice q/k/v writes happen only after all waves pass the
        // post-attention barrier; obuf rewrite is fenced by next slice's barrier 1.
    }

    // ---------- write / accumulate output ----------
    #pragma unroll
    for (int mt = 0; mt < 2; ++mt)
        #pragma unroll
        for (int nt = 0; nt < 2; ++nt)
            #pragma unroll
            for (int r = 0; r < 4; ++r) {
                const int pos = mt * 16 + lk * 4 + r;
                const int c = w * 32 + nt * 16 + lr;
                const int gy = (AXIS == 0) ? pos : line;
                const int gx = (AXIS == 0) ? line : pos;
                float* po = out + ((size_t)((b * 32 + gy) * 32 + gx)) * 256 + c;
                if (ACCUM) *po += oacc[mt][nt][r];
                else       *po = oacc[mt][nt][r];
            }
}

} // namespace

extern "C" void kernel_launch(void* const* d_in, const int* in_sizes, int n_in,
                              void* d_out, int out_size, void* d_ws, size_t ws_size,
                              hipStream_t stream) {
    (void)in_sizes; (void)n_in; (void)out_size; (void)ws_size;
    const float* x     = (const float*)d_in[0];
    const float* xpos  = (const float*)d_in[1];
    const float* ypos  = (const float*)d_in[2];
    const float* Wq    = (const float*)d_in[3];
    const float* Wk    = (const float*)d_in[4];
    const float* Wv    = (const float*)d_in[5];
    const float* bv    = (const float*)d_in[6];
    const float* Wo    = (const float*)d_in[7];
    const float* rfreq = (const float*)d_in[8];
    float* out = (float*)d_out;

    short* wsQ  = (short*)d_ws;                 // 1 MB
    short* wsKV = wsQ + 1024 * 512;             // 1 MB
    short* wsO  = wsKV + 1024 * 512;            // 1 MB
    float2* csTab = (float2*)(wsO + 1024 * 512); // 64 KB: [axis][pos][r]

    prep_weights<<<dim3(800), dim3(256), 0, stream>>>(
        Wq, Wk, Wv, Wo, xpos, ypos, rfreq, wsQ, wsKV, wsO, csTab);
    axial_attn_mfma<0, false><<<dim3(1024), dim3(512), 0, stream>>>(
        x, bv, csTab, wsQ, wsKV, wsO, out);
    axial_attn_mfma<1, true><<<dim3(1024), dim3(512), 0, stream>>>(
        x, bv, csTab + 4096, wsQ, wsKV, wsO, out);
}

// Round 18
// 267.514 us; speedup vs baseline: 2.0085x; 2.0085x over previous
//
#include <hip/hip_runtime.h>
#include <math.h>

namespace {

typedef __attribute__((ext_vector_type(8))) short short8;
typedef __attribute__((ext_vector_type(4))) float f32x4;

constexpr float kPI = 3.14159265358979323846f;

__device__ __forceinline__ unsigned short f2bf(float f) {
    unsigned int u = __float_as_uint(f);
    u += 0x7fffu + ((u >> 16) & 1u);
    return (unsigned short)(u >> 16);
}

__device__ __forceinline__ short8 pack8(const float* f) {
    short8 r;
    #pragma unroll
    for (int i = 0; i < 8; ++i) r[i] = (short)f2bf(f[i]);
    return r;
}

__device__ __forceinline__ f32x4 MFMA(short8 a, short8 b, f32x4 c) {
    return __builtin_amdgcn_mfma_f32_16x16x32_bf16(a, b, c, 0, 0, 0);
}

// ---- weight pre-arrangement into B-fragment order (bf16) ----
// chunk = (adv, kstep, ntile): 64 lanes x 8 bf16; lane l holds
// B[k = kstep*32 + (l>>4)*8 + i][col = ntile*16 + (l&15)].
__global__ __launch_bounds__(256)
void prep_weights(const float* __restrict__ Wq, const float* __restrict__ Wk,
                  const float* __restrict__ Wv, const float* __restrict__ Wo,
                  short* __restrict__ wsQ, short* __restrict__ wsKV,
                  short* __restrict__ wsO)
{
    const int cid = blockIdx.x * 4 + (threadIdx.x >> 6);
    const int l = threadIdx.x & 63;
    const int lr = l & 15, lk = l >> 4;
    const int arr = cid >> 10, c2 = cid & 1023;
    const int adv = c2 >> 7, ks = (c2 >> 4) & 7, nt = c2 & 15;
    const int c0 = ks * 32 + lk * 8;
    float v[8];
    if (arr == 0) {                       // Wq[c][adv][j], j in [0,256)
        const int j = nt * 16 + lr;
        #pragma unroll
        for (int i = 0; i < 8; ++i)
            v[i] = Wq[((size_t)(c0 + i) * 8 + adv) * 256 + j];
    } else if (arr == 1) {                // K (nt<8) then V (nt>=8), j in [0,128)
        if (nt < 8) {
            const int j = nt * 16 + lr;
            #pragma unroll
            for (int i = 0; i < 8; ++i)
                v[i] = Wk[((size_t)(c0 + i) * 8 + adv) * 128 + j];
        } else {
            const int j = (nt - 8) * 16 + lr;
            #pragma unroll
            for (int i = 0; i < 8; ++i)
                v[i] = Wv[((size_t)(c0 + i) * 8 + adv) * 128 + j];
        }
    } else {                              // Wo[adv][j][c]: k=j, col=c
        const int cc = nt * 16 + lr;
        #pragma unroll
        for (int i = 0; i < 8; ++i)
            v[i] = Wo[((size_t)adv * 256 + (c0 + i)) * 256 + cc];
    }
    short* dst = (arr == 0 ? wsQ : arr == 1 ? wsKV : wsO) + (size_t)c2 * 512 + l * 8;
    *(short8*)dst = pack8(v);
}

// ---- fused per-line axial attention; all four GEMMs + attention on MFMA ----
// block = (b, line); 512 threads = 8 waves. Attention: wave w = group g = (m*4+kk).
// LDS = 73.3 KB -> 2 blocks/CU under __launch_bounds__(512,4) (128-reg budget).
// k-loops unroll-capped to 2 (round-9) AND RoPE epilogue loops unroll-capped
// to 1 (round-10). This is the measured session optimum (268.9 us total):
// the residual ~110 MB/dispatch scratch traffic overlaps with compute better
// than every spill-free alternative (rounds 11-17 all regressed).
template <int AXIS, bool ACCUM>
__global__ __launch_bounds__(512, 4)
void axial_attn_mfma(const float* __restrict__ x,
                     const float* __restrict__ xpos,
                     const float* __restrict__ ypos,
                     const float* __restrict__ bvp,
                     const float* __restrict__ rfreq,
                     const short* __restrict__ wsQ,
                     const short* __restrict__ wsKV,
                     const short* __restrict__ wsO,
                     float* __restrict__ out)
{
    __shared__ __align__(16) short xs[32 * 256];    // x line bf16, elem ^ ((row&7)<<3)
    __shared__ __align__(16) short qbuf[32 * 256];  // Qr bf16, same swizzle
    __shared__ __align__(16) short kbuf[32 * 256];  // Kr bf16 (with m), same swizzle
    __shared__ __align__(16) short vbuf[4 * 32 * 32]; // V^T bf16 [kk][dv][s ^ ((dv&3)<<3)]
    __shared__ __align__(16) short obuf[32 * 256];  // attn out bf16, same swizzle
    __shared__ float2 posf[32];                     // pos coords
    __shared__ float2 rfs[128];                     // pre-scaled rope freqs [m*64+kk*16+h]

    const int t = threadIdx.x;
    const int b = blockIdx.x >> 5;
    const int line = blockIdx.x & 31;
    const int w = t >> 6, l = t & 63;
    const int lr = l & 15, lk = l >> 4;
    const int p01 = l & 1;

    // ---- stage x line into xs (bf16, swizzled): 16 elems/thread ----
    {
        const int row = t >> 4;
        const int c0 = (t & 15) * 16;
        const int gy = (AXIS == 0) ? row : line;
        const int gx = (AXIS == 0) ? line : row;
        const float* px = x + ((size_t)((b * 32 + gy) * 32 + gx)) * 256 + c0;
        float tmp[16];
        #pragma unroll
        for (int i = 0; i < 16; i += 4) {
            const float4 a = *(const float4*)(px + i);
            tmp[i] = a.x; tmp[i + 1] = a.y; tmp[i + 2] = a.z; tmp[i + 3] = a.w;
        }
        const int swz = (row & 7) << 3;
        *(short8*)&xs[row * 256 + (c0 ^ swz)] = pack8(tmp);
        *(short8*)&xs[row * 256 + ((c0 + 8) ^ swz)] = pack8(tmp + 8);
    }
    // ---- tiny RoPE tables ----
    const float* posv = (AXIS == 0) ? ypos : xpos;
    if (t < 128) {
        const int h = t & 15;
        const float s0 = kPI / (1.0f + (29.0f / 15.0f) * (float)h);
        const float s1 = kPI / (0.1f + 0.06f * (float)h);
        rfs[t] = make_float2(rfreq[2 * t] * s0, rfreq[2 * t + 1] * s1);
    }
    if (t < 32) posf[t] = make_float2(posv[2 * t], posv[2 * t + 1]);
    __syncthreads();

    f32x4 oacc[2][2] = {};
    const short8* wsQv  = (const short8*)wsQ;
    const short8* wsKVv = (const short8*)wsKV;
    const short8* wsOv  = (const short8*)wsO;
    const int m_w = w >> 2, kk_w = w & 3;
    const int aswz = (lr & 7) << 3;   // row&7 == lr&7 for rows lr and 16+lr

    for (int dvi = 0; dvi < 4; ++dvi) {
        const int adv = AXIS * 4 + dvi;
        const float sgn = (dvi < 2) ? 1.0f : -1.0f;   // d = dvi>>1

        // ---------- Q projection + RoPE (recomputed) -> qbuf bf16 ----------
        {
            f32x4 acc[2][2] = {};
            #pragma unroll 2
            for (int ks = 0; ks < 8; ++ks) {
                const int e = (ks * 32 + lk * 8) ^ aswz;
                const short8 a0 = *(const short8*)&xs[lr * 256 + e];
                const short8 a1 = *(const short8*)&xs[(16 + lr) * 256 + e];
                const short8 b0 = wsQv[(size_t)((adv * 8 + ks) * 16 + w * 2 + 0) * 64 + l];
                const short8 b1 = wsQv[(size_t)((adv * 8 + ks) * 16 + w * 2 + 1) * 64 + l];
                acc[0][0] = MFMA(a0, b0, acc[0][0]);
                acc[1][0] = MFMA(a1, b0, acc[1][0]);
                acc[0][1] = MFMA(a0, b1, acc[0][1]);
                acc[1][1] = MFMA(a1, b1, acc[1][1]);
            }
            #pragma unroll 1
            for (int mt = 0; mt < 2; ++mt)
                #pragma unroll 1
                for (int nt = 0; nt < 2; ++nt) {
                    const int h = (nt * 16 + lr) >> 1;
                    const float2 rf = rfs[m_w * 64 + kk_w * 16 + h];
                    #pragma unroll
                    for (int r = 0; r < 4; ++r) {
                        const float own = acc[mt][nt][r];
                        const float oth = __shfl_xor(own, 1);
                        const int pos = mt * 16 + lk * 4 + r;
                        const float2 pp = posf[pos];
                        float sv, cv;
                        __sincosf(rf.x * pp.x + rf.y * pp.y, &sv, &cv);
                        const float rv = (p01 == 0) ? cv * own + sgn * sv * oth
                                                    : cv * own - sgn * sv * oth;
                        const int col = w * 32 + nt * 16 + lr;
                        qbuf[pos * 256 + (col ^ ((pos & 7) << 3))] = (short)f2bf(rv);
                    }
                }
        }

        // ---------- K/V projection (waves 0-3: K both m; waves 4-7: V^T) ----------
        {
            f32x4 acc[2][2] = {};
            #pragma unroll 2
            for (int ks = 0; ks < 8; ++ks) {
                const int e = (ks * 32 + lk * 8) ^ aswz;
                const short8 a0 = *(const short8*)&xs[lr * 256 + e];
                const short8 a1 = *(const short8*)&xs[(16 + lr) * 256 + e];
                const short8 b0 = wsKVv[(size_t)((adv * 8 + ks) * 16 + w * 2 + 0) * 64 + l];
                const short8 b1 = wsKVv[(size_t)((adv * 8 + ks) * 16 + w * 2 + 1) * 64 + l];
                acc[0][0] = MFMA(a0, b0, acc[0][0]);
                acc[1][0] = MFMA(a1, b0, acc[1][0]);
                acc[0][1] = MFMA(a0, b1, acc[0][1]);
                acc[1][1] = MFMA(a1, b1, acc[1][1]);
            }
            if (w < 4) {
                #pragma unroll 1
                for (int mt = 0; mt < 2; ++mt)
                    #pragma unroll 1
                    for (int nt = 0; nt < 2; ++nt) {
                        const int h = (nt * 16 + lr) >> 1;
                        const float2 rf0 = rfs[w * 16 + h];
                        const float2 rf1 = rfs[64 + w * 16 + h];
                        #pragma unroll
                        for (int r = 0; r < 4; ++r) {
                            const float own = acc[mt][nt][r];
                            const float oth = __shfl_xor(own, 1);
                            const int pos = mt * 16 + lk * 4 + r;
                            const float2 pp = posf[pos];
                            #pragma unroll
                            for (int m2 = 0; m2 < 2; ++m2) {
                                const float2 rf = (m2 == 0) ? rf0 : rf1;
                                float sv, cv;
                                __sincosf(rf.x * pp.x + rf.y * pp.y, &sv, &cv);
                                const float rv = (p01 == 0) ? cv * own + sgn * sv * oth
                                                            : cv * own - sgn * sv * oth;
                                const int col = (m2 * 4 + w) * 32 + nt * 16 + lr;
                                kbuf[pos * 256 + (col ^ ((pos & 7) << 3))] = (short)f2bf(rv);
                            }
                        }
                    }
            } else {
                const int kk = w - 4;
                #pragma unroll
                for (int nt = 0; nt < 2; ++nt) {
                    const int dv = nt * 16 + lr;
                    const float bvv = bvp[adv * 128 + kk * 32 + dv];
                    #pragma unroll
                    for (int mt = 0; mt < 2; ++mt)
                        #pragma unroll
                        for (int r = 0; r < 4; ++r) {
                            const int s = mt * 16 + lk * 4 + r;
                            // swizzle restricted to bits 3-4: s has only 5 bits.
                            vbuf[kk * 1024 + dv * 32 + (s ^ ((dv & 3) << 3))] =
                                (short)f2bf(acc[mt][nt][r] + bvv);
                        }
                }
            }
        }
        __syncthreads();

        // ---------- attention (MFMA): wave g; scores^T = mfma(Kr, Qr) ----------
        {
            const int g = w;
            short8 ka[2], qa[2];
            #pragma unroll
            for (int st = 0; st < 2; ++st) {
                const int row = st * 16 + lr;
                ka[st] = *(const short8*)&kbuf[row * 256 + ((g * 32 + lk * 8) ^ ((row & 7) << 3))];
            }
            #pragma unroll
            for (int qt = 0; qt < 2; ++qt) {
                const int row = qt * 16 + lr;
                qa[qt] = *(const short8*)&qbuf[row * 256 + ((g * 32 + lk * 8) ^ ((row & 7) << 3))];
            }
            f32x4 d[2][2] = {};
            #pragma unroll
            for (int st = 0; st < 2; ++st)
                #pragma unroll
                for (int qt = 0; qt < 2; ++qt)
                    d[st][qt] = MFMA(ka[st], qa[qt], d[st][qt]);

            // sigmoid + pack pairs (consecutive s) to bf16 — plain bit ops
            unsigned int pk[2][2][2];
            #pragma unroll
            for (int st = 0; st < 2; ++st)
                #pragma unroll
                for (int qt = 0; qt < 2; ++qt)
                    #pragma unroll
                    for (int h2 = 0; h2 < 2; ++h2) {
                        const float za = __builtin_amdgcn_rcpf(1.0f + __expf(-d[st][qt][2 * h2]));
                        const float zb = __builtin_amdgcn_rcpf(1.0f + __expf(-d[st][qt][2 * h2 + 1]));
                        pk[st][qt][h2] = (unsigned int)f2bf(za) |
                                         ((unsigned int)f2bf(zb) << 16);
                    }

            // redistribute D^T -> P A-frag: lane (lk,lr) needs P[s=lk*8+i][q=qt*16+lr]
            const int srcA = ((lk & 1) * 2) * 16 + lr;
            short8 pa[2];
            #pragma unroll
            for (int qt = 0; qt < 2; ++qt) {
                union { unsigned int u[4]; short8 s; } uu;
                #pragma unroll
                for (int jp = 0; jp < 4; ++jp) {
                    const int src = srcA + (jp >> 1) * 16;
                    const int v0 = __shfl((int)pk[0][qt][jp & 1], src, 64);
                    const int v1 = __shfl((int)pk[1][qt][jp & 1], src, 64);
                    uu.u[jp] = (lk < 2) ? (unsigned int)v0 : (unsigned int)v1;
                }
                pa[qt] = uu.s;
            }

            // PV: B-frag from V^T; o[q][dv]
            const int kkg = g & 3;
            short8 vb2[2];
            #pragma unroll
            for (int dvt = 0; dvt < 2; ++dvt) {
                const int dv = dvt * 16 + lr;
                vb2[dvt] = *(const short8*)&vbuf[kkg * 1024 + dv * 32 + ((lk * 8) ^ ((dv & 3) << 3))];
            }
            f32x4 o2[2][2] = {};
            #pragma unroll
            for (int qt = 0; qt < 2; ++qt)
                #pragma unroll
                for (int dvt = 0; dvt < 2; ++dvt)
                    o2[qt][dvt] = MFMA(pa[qt], vb2[dvt], o2[qt][dvt]);

            // write o -> obuf bf16 (swizzled like qbuf)
            #pragma unroll
            for (int qt = 0; qt < 2; ++qt)
                #pragma unroll
                for (int dvt = 0; dvt < 2; ++dvt)
                    #pragma unroll
                    for (int r = 0; r < 4; ++r) {
                        const int q = qt * 16 + lk * 4 + r;
                        const int col = g * 32 + dvt * 16 + lr;
                        obuf[q * 256 + (col ^ ((q & 7) << 3))] = (short)f2bf(o2[qt][dvt][r]);
                    }
        }
        __syncthreads();

        // ---------- out projection: oacc += o(bf16) x Wo_frag ----------
        {
            #pragma unroll 2
            for (int ks = 0; ks < 8; ++ks) {
                const int e = (ks * 32 + lk * 8) ^ aswz;
                const short8 a0 = *(const short8*)&obuf[lr * 256 + e];
                const short8 a1 = *(const short8*)&obuf[(16 + lr) * 256 + e];
                const short8 b0 = wsOv[(size_t)((adv * 8 + ks) * 16 + w * 2 + 0) * 64 + l];
                const short8 b1 = wsOv[(size_t)((adv * 8 + ks) * 16 + w * 2 + 1) * 64 + l];
                oacc[0][0] = MFMA(a0, b0, oacc[0][0]);
                oacc[1][0] = MFMA(a1, b0, oacc[1][0]);
                oacc[0][1] = MFMA(a0, b1, oacc[0][1]);
                oacc[1][1] = MFMA(a1, b1, oacc[1][1]);
            }
        }
        // next-slice q/k/v writes happen only after all waves pass the
        // post-attention barrier; obuf rewrite is fenced by next slice's barrier 1.
    }

    // ---------- write / accumulate output ----------
    #pragma unroll
    for (int mt = 0; mt < 2; ++mt)
        #pragma unroll
        for (int nt = 0; nt < 2; ++nt)
            #pragma unroll
            for (int r = 0; r < 4; ++r) {
                const int pos = mt * 16 + lk * 4 + r;
                const int c = w * 32 + nt * 16 + lr;
                const int gy = (AXIS == 0) ? pos : line;
                const int gx = (AXIS == 0) ? line : pos;
                float* po = out + ((size_t)((b * 32 + gy) * 32 + gx)) * 256 + c;
                if (ACCUM) *po += oacc[mt][nt][r];
                else       *po = oacc[mt][nt][r];
            }
}

} // namespace

extern "C" void kernel_launch(void* const* d_in, const int* in_sizes, int n_in,
                              void* d_out, int out_size, void* d_ws, size_t ws_size,
                              hipStream_t stream) {
    (void)in_sizes; (void)n_in; (void)out_size; (void)ws_size;
    const float* x     = (const float*)d_in[0];
    const float* xpos  = (const float*)d_in[1];
    const float* ypos  = (const float*)d_in[2];
    const float* Wq    = (const float*)d_in[3];
    const float* Wk    = (const float*)d_in[4];
    const float* Wv    = (const float*)d_in[5];
    const float* bv    = (const float*)d_in[6];
    const float* Wo    = (const float*)d_in[7];
    const float* rfreq = (const float*)d_in[8];
    float* out = (float*)d_out;

    short* wsQ  = (short*)d_ws;                 // 1 MB
    short* wsKV = wsQ + 1024 * 512;             // 1 MB
    short* wsO  = wsKV + 1024 * 512;            // 1 MB

    prep_weights<<<dim3(768), dim3(256), 0, stream>>>(Wq, Wk, Wv, Wo, wsQ, wsKV, wsO);
    axial_attn_mfma<0, false><<<dim3(1024), dim3(512), 0, stream>>>(
        x, xpos, ypos, bv, rfreq, wsQ, wsKV, wsO, out);
    axial_attn_mfma<1, true><<<dim3(1024), dim3(512), 0, stream>>>(
        x, xpos, ypos, bv, rfreq, wsQ, wsKV, wsO, out);
}